// Round 1
// baseline (454.255 us; speedup 1.0000x reference)
//
#include <hip/hip_runtime.h>

#define BB 4
#define TT 1024
#define CCH 2048
#define HH 16
#define HDIM 128
#define NBLK 1024
#define MM (BB*TT)          // 4096
#define N1 (3*CCH)          // 6144
#define NQT 16              // T / 64

typedef _Float16 f16;
typedef _Float16 half8 __attribute__((ext_vector_type(8)));
typedef _Float16 half4 __attribute__((ext_vector_type(4)));
typedef float floatx4 __attribute__((ext_vector_type(4)));

// async global->LDS, 16B per lane. LDS dest = wave-uniform base + lane*16.
__device__ __forceinline__ void g2lds16(const void* g, void* l) {
    __builtin_amdgcn_global_load_lds((const __attribute__((address_space(1))) void*)g,
                                     (__attribute__((address_space(3))) void*)l, 16, 0, 0);
}

// ---- fused prep: z=0 transpose Wa -> WaT f16, z=1 Wp -> WpT, z=2 cvt x -> f16 ----
__global__ void k_prep(const float* __restrict__ Wa, const float* __restrict__ Wp,
                       const float* __restrict__ x,
                       f16* __restrict__ WaT, f16* __restrict__ WpT,
                       f16* __restrict__ x16) {
    int z = blockIdx.z;
    if (z == 2) {   // convert: MM*CCH/4 float4s
        int i = (blockIdx.y * 192 + blockIdx.x) * 256 + threadIdx.x + threadIdx.y * 32;
        if (i >= MM * CCH / 4) return;
        float4 v = ((const float4*)x)[i];
        union { ushort4 u; f16 h[4]; } o;
        o.h[0] = (f16)v.x; o.h[1] = (f16)v.y; o.h[2] = (f16)v.z; o.h[3] = (f16)v.w;
        ((ushort4*)x16)[i] = o.u;
        return;
    }
    const float* in = (z == 0) ? Wa : Wp;
    f16* out = (z == 0) ? WaT : WpT;
    int Cc = (z == 0) ? N1 : CCH;
    if (blockIdx.x * 32 >= Cc) return;
    __shared__ float tile[32][33];
    int c0 = blockIdx.x * 32, r0 = blockIdx.y * 32;
    int tx = threadIdx.x, ty = threadIdx.y;
#pragma unroll
    for (int k = 0; k < 4; k++) {
        int r = ty + k * 8;
        tile[r][tx] = in[(size_t)(r0 + r) * Cc + c0 + tx];
    }
    __syncthreads();
#pragma unroll
    for (int k = 0; k < 4; k++) {
        int r = ty + k * 8;
        out[(size_t)(c0 + r) * CCH + r0 + tx] = (f16)tile[tx][r];
    }
}

// ------- transpose f16 per-head [T][HD] -> [HD][T] (for V) -------
__global__ void k_trv(const f16* __restrict__ in, f16* __restrict__ out) {
    __shared__ f16 tile[32][34];
    int bh = blockIdx.z;
    int h0 = blockIdx.x * 32, t0 = blockIdx.y * 32;
    int tx = threadIdx.x, ty = threadIdx.y;
#pragma unroll
    for (int k = 0; k < 4; k++) {
        int t = ty + k * 8;
        tile[t][tx] = in[((size_t)bh * TT + t0 + t) * HDIM + h0 + tx];
    }
    __syncthreads();
#pragma unroll
    for (int k = 0; k < 4; k++) {
        int r = ty + k * 8;
        out[((size_t)bh * HDIM + h0 + r) * TT + t0 + tx] = tile[tx][r];
    }
}

// ---------------- global histogram over all B*T tokens ----------------
__global__ void k_hist(const int* __restrict__ tok, int* __restrict__ cnt) {
    int i = blockIdx.x * blockDim.x + threadIdx.x;
    if (i < MM) atomicAdd(cnt + tok[i], 1);
}

// ------- per-batch inclusive scan of 1/count; also padding bias -------
__global__ __launch_bounds__(1024) void k_scan(const int* __restrict__ tok,
                                               const int* __restrict__ cnt,
                                               const int* __restrict__ pm,
                                               float* __restrict__ tpos,
                                               float* __restrict__ pb) {
    __shared__ float s[TT];
    int b = blockIdx.x, t = threadIdx.x;
    s[t] = 1.0f / ((float)cnt[tok[b * TT + t]] + 1e-10f);
    __syncthreads();
    for (int off = 1; off < TT; off <<= 1) {
        float add = (t >= off) ? s[t - off] : 0.0f;
        __syncthreads();
        s[t] += add;
        __syncthreads();
    }
    tpos[b * TT + t] = s[t];
    pb[b * TT + t] = pm[b * TT + t] ? 0.0f : -1e30f;
}

// ------- rope table: tab[row*64+j] = (cos, sin) of tpos[row]*10000^(-j/64) -------
__global__ void k_rope(const float* __restrict__ tpos, float2* __restrict__ tab) {
    int i = blockIdx.x * 256 + threadIdx.x;     // MM*64 entries
    int row = i >> 6, j = i & 63;
    float f = tpos[row] * expf((float)j * -0.14391156929f);   // ln(10000)/64
    float sn, cn; sincosf(f, &sn, &cn);
    tab[i] = make_float2(cn, sn);
}

// ================= 256x256 8-phase GEMM (BK=64, 8 waves, dbuf LDS) =================
// A[M][2048] f16, Bt[N][2048] f16. Per-wave 128x64 output (acc[8][4] floatx4).
// T2: st_16x32 XOR swizzle (byte ^= ((byte>>9)&1)<<5), applied to BOTH the
//     pre-swizzled global source of global_load_lds (linear LDS dest) and the
//     ds_read addresses (rule 21: both-sides-or-neither).
// T3/T4: 8 phases/iter (2 K-tiles), 1 half-tile staged per phase, counted
//     s_waitcnt vmcnt(6) ONLY at phases 4 and 8 (raw s_barrier everywhere so
//     the compiler can't re-insert vmcnt(0) drains).
// T5: setprio(1) around each 16-MFMA cluster.
// Stage windows derived from frag-read completion: A free @3 (read ph1,2),
// B.h0 free @2 (read ph1), B.h1 free @4 (read ph3) -> slots {2:Bh0,3:Ah0,
// 4:Ah1,5:Bh1} for tile t+2 and {6:Bh0,7:Ah0,8:Ah1,1':Bh1} for t+3; at the
// ph4/ph8 waits exactly 3 half-tiles (6 loads) are newer than the needed set.
// B-frag col remap (nf stride 64): wave wn owns cols wn*16 + nf*64 + l16, so
// each rope pair (d, d+64) = (nf even, nf odd) stays inside one wave.
#define RA(buf, mf, kk) (*(const half8*)((const char*)As + ((buf) << 15) + ((aoffb + ((mf) << 11) + ((kk) << 6)) ^ flip)))
#define RB(buf, nf, kk) (*(const half8*)((const char*)Bs + ((buf) << 15) + ((boffb + ((nf) << 13) + ((kk) << 6)) ^ flip)))
#define STAGE(P, L, h, t) do { \
    g2lds16((P) + (size_t)(((h) << 7) + ro0) * 2048 + ((t) << 6) + co0, (L) + ((h) << 13) + (w << 9)); \
    g2lds16((P) + (size_t)(((h) << 7) + ro1) * 2048 + ((t) << 6) + co1, (L) + ((h) << 13) + ((8 + w) << 9)); \
} while (0)
#define MFMAQ(AF, BF, M0, N0) do { \
  _Pragma("unroll") for (int m_ = 0; m_ < 4; m_++) \
  _Pragma("unroll") for (int n_ = 0; n_ < 2; n_++) \
  _Pragma("unroll") for (int k_ = 0; k_ < 2; k_++) \
    acc[(M0) + m_][(N0) + n_] = __builtin_amdgcn_mfma_f32_16x16x32_f16(AF[m_][k_], BF[n_][k_], acc[(M0) + m_][(N0) + n_], 0, 0, 0); \
} while (0)
#define BAR() __builtin_amdgcn_s_barrier()
#define WLG0() asm volatile("s_waitcnt lgkmcnt(0)" ::: "memory")

template <int MODE>   // 1: QKV fused rope epilogue (N=6144); 0: plain f32 C (N=2048)
__global__ __launch_bounds__(512, 2) void k_gemm8(const f16* __restrict__ A,
                                                  const f16* __restrict__ Bt,
                                                  float* __restrict__ Cp,
                                                  const float2* __restrict__ tab,
                                                  const float* __restrict__ cs,
                                                  f16* __restrict__ qr,
                                                  f16* __restrict__ kr,
                                                  f16* __restrict__ vsc) {
    const float SCALE = 0.08838834764831845f;   // 1/sqrt(128), folded into q
    const int NBN = MODE ? 24 : 8;
    const int NWG = MODE ? 384 : 128;
    const int CPX = NWG >> 3;
    __shared__ __align__(16) f16 As[2 * 16384];   // [buf][256][64], 64KB
    __shared__ __align__(16) f16 Bs[2 * 16384];   // [buf][256][64], 64KB

    int bid = blockIdx.x;
    int s = (bid & 7) * CPX + (bid >> 3);          // XCD-aware swizzle (bijective: NWG%8==0)
    int bm = s / NBN, bn = s % NBN;

    int tid = threadIdx.x;
    int w = tid >> 6, lane = tid & 63, quad = lane >> 4, l16 = lane & 15;
    int wm = w >> 2, wn = w & 3;                   // 2 x 4 wave grid

    const f16* Ab = A + (size_t)(bm << 8) * 2048;
    const f16* Bb = Bt + (size_t)(bn << 8) * 2048;

    // staging source offsets (pre-swizzled so linear LDS writes land swizzled)
    int db0 = (w << 10) + (lane << 4);
    int db1 = ((8 + w) << 10) + (lane << 4);
    int sb0 = db0 ^ (((db0 >> 9) & 1) << 5);
    int sb1 = db1 ^ (((db1 >> 9) & 1) << 5);
    int ro0 = sb0 >> 7, co0 = (sb0 & 127) >> 1;
    int ro1 = sb1 >> 7, co1 = (sb1 & 127) >> 1;

    // frag-read swizzled base offsets (bit9 of the linear offset == l16&4)
    const int flip = (l16 & 4) << 3;               // 0 or 32
    const int aoffb = ((wm * 128 + l16) << 7) + (quad << 4);
    const int boffb = ((wn * 16 + l16) << 7) + (quad << 4);

    floatx4 acc[8][4];
#pragma unroll
    for (int i = 0; i < 8; i++)
#pragma unroll
        for (int j = 0; j < 4; j++) acc[i][j] = (floatx4){0.f, 0.f, 0.f, 0.f};

    // ---- prologue: tile0 (4 halves) + tile1 (Bh0,Ah0,Ah1); Bh1(1) comes in ph1
    STAGE(Bb, Bs, 0, 0);
    STAGE(Ab, As, 0, 0);
    STAGE(Ab, As, 1, 0);
    STAGE(Bb, Bs, 1, 0);
    STAGE(Bb, Bs + 16384, 0, 1);
    STAGE(Ab, As + 16384, 0, 1);
    STAGE(Ab, As + 16384, 1, 1);
    asm volatile("s_waitcnt vmcnt(6)" ::: "memory");   // tile0 fully landed
    BAR();

#pragma unroll 1
    for (int it = 0; it < 16; ++it) {
        const int t1 = 2 * it + 1, t2 = 2 * it + 2, t3 = 2 * it + 3;
        const bool g2 = (t2 < 32), g3 = (t3 < 32);
        half8 af0[4][2], af1[4][2], bf0[2][2], bf1[2][2];
        // ---- phase 1 (buf0): reads A.mh0(8) + B.nh0(4); stage Bh1(t1)->buf1
#pragma unroll
        for (int m = 0; m < 4; m++) { af0[m][0] = RA(0, m, 0); af0[m][1] = RA(0, m, 1); }
#pragma unroll
        for (int n = 0; n < 2; n++) { bf0[n][0] = RB(0, n, 0); bf0[n][1] = RB(0, n, 1); }
        STAGE(Bb, Bs + 16384, 1, t1);
        asm volatile("s_waitcnt lgkmcnt(8)" ::: "memory");
        BAR(); WLG0();
        __builtin_amdgcn_s_setprio(1); MFMAQ(af0, bf0, 0, 0); __builtin_amdgcn_s_setprio(0);
        BAR();
        // ---- phase 2: reads A.mh1(8); stage Bh0(t2)->buf0
#pragma unroll
        for (int m = 0; m < 4; m++) { af1[m][0] = RA(0, 4 + m, 0); af1[m][1] = RA(0, 4 + m, 1); }
        if (g2) STAGE(Bb, Bs, 0, t2);
        BAR(); WLG0();
        __builtin_amdgcn_s_setprio(1); MFMAQ(af1, bf0, 4, 0); __builtin_amdgcn_s_setprio(0);
        BAR();
        // ---- phase 3: reads B.nh1(4); stage Ah0(t2)->buf0
#pragma unroll
        for (int n = 0; n < 2; n++) { bf1[n][0] = RB(0, 2 + n, 0); bf1[n][1] = RB(0, 2 + n, 1); }
        if (g2) STAGE(Ab, As, 0, t2);
        BAR(); WLG0();
        __builtin_amdgcn_s_setprio(1); MFMAQ(af1, bf1, 4, 2); __builtin_amdgcn_s_setprio(0);
        BAR();
        // ---- phase 4: stage Ah1(t2)->buf0; counted vmcnt (tile t1 now complete)
        if (g2) STAGE(Ab, As, 1, t2);
        BAR();
        __builtin_amdgcn_s_setprio(1); MFMAQ(af0, bf1, 0, 2); __builtin_amdgcn_s_setprio(0);
        if (it < 15) { asm volatile("s_waitcnt vmcnt(6)" ::: "memory"); }
        else         { asm volatile("s_waitcnt vmcnt(0)" ::: "memory"); }
        BAR();
        // ---- phase 5 (buf1): reads; stage Bh1(t2)->buf0
#pragma unroll
        for (int m = 0; m < 4; m++) { af0[m][0] = RA(1, m, 0); af0[m][1] = RA(1, m, 1); }
#pragma unroll
        for (int n = 0; n < 2; n++) { bf0[n][0] = RB(1, n, 0); bf0[n][1] = RB(1, n, 1); }
        if (g2) STAGE(Bb, Bs, 1, t2);
        asm volatile("s_waitcnt lgkmcnt(8)" ::: "memory");
        BAR(); WLG0();
        __builtin_amdgcn_s_setprio(1); MFMAQ(af0, bf0, 0, 0); __builtin_amdgcn_s_setprio(0);
        BAR();
        // ---- phase 6: stage Bh0(t3)->buf1
#pragma unroll
        for (int m = 0; m < 4; m++) { af1[m][0] = RA(1, 4 + m, 0); af1[m][1] = RA(1, 4 + m, 1); }
        if (g3) STAGE(Bb, Bs + 16384, 0, t3);
        BAR(); WLG0();
        __builtin_amdgcn_s_setprio(1); MFMAQ(af1, bf0, 4, 0); __builtin_amdgcn_s_setprio(0);
        BAR();
        // ---- phase 7: stage Ah0(t3)->buf1
#pragma unroll
        for (int n = 0; n < 2; n++) { bf1[n][0] = RB(1, 2 + n, 0); bf1[n][1] = RB(1, 2 + n, 1); }
        if (g3) STAGE(Ab, As + 16384, 0, t3);
        BAR(); WLG0();
        __builtin_amdgcn_s_setprio(1); MFMAQ(af1, bf1, 4, 2); __builtin_amdgcn_s_setprio(0);
        BAR();
        // ---- phase 8: stage Ah1(t3)->buf1; counted vmcnt (tile t2 complete)
        if (g3) STAGE(Ab, As + 16384, 1, t3);
        BAR();
        __builtin_amdgcn_s_setprio(1); MFMAQ(af0, bf1, 0, 2); __builtin_amdgcn_s_setprio(0);
        if (it < 15) { asm volatile("s_waitcnt vmcnt(6)" ::: "memory"); }
        else         { asm volatile("s_waitcnt vmcnt(0)" ::: "memory"); }
        BAR();
    }

    // ---- epilogue: rows = bm*256 + wm*128 + mf*16 + quad*4 + r
    //      cols = bn*256 + wn*16 + nf*64 + l16
    if (MODE == 0) {
#pragma unroll
        for (int mf = 0; mf < 8; mf++)
#pragma unroll
            for (int nf = 0; nf < 4; nf++) {
                int col = (bn << 8) + wn * 16 + nf * 64 + l16;
#pragma unroll
                for (int r = 0; r < 4; r++) {
                    int row = (bm << 8) + wm * 128 + mf * 16 + (quad << 2) + r;
                    Cp[(size_t)row * CCH + col] = acc[mf][nf][r];
                }
            }
    } else {
        int type = bn >> 3;              // 0=q, 1=k, 2=v (8 blocks per 2048-col chunk)
        int h0 = (bn * 2) & 15;          // first of the block's 2 heads
        int d1 = wn * 16 + l16;          // 0..63 (low half of head dim)
        if (type < 2) {
            f16* outp = (type == 0) ? qr : kr;
#pragma unroll
            for (int mf = 0; mf < 8; mf++)
#pragma unroll
                for (int r = 0; r < 4; r++) {
                    int row = (bm << 8) + wm * 128 + mf * 16 + (quad << 2) + r;
                    float2 tc = tab[row * 64 + d1];
#pragma unroll
                    for (int p = 0; p < 2; p++) {     // head pair: nf {0,1} and {2,3}
                        float a1 = acc[mf][2 * p][r], a2 = acc[mf][2 * p + 1][r];
                        float o1 = a1 * tc.x - a2 * tc.y;
                        float o2 = a2 * tc.x + a1 * tc.y;
                        if (type == 0) {
                            if (d1 == 63) o2 = 1.0f;          // q[...,-1]=1 (before scale)
                            o1 *= SCALE; o2 *= SCALE;
                        } else {
                            if (d1 == 63) o2 = cs[row];       // k[...,-1]=cum_scores
                        }
                        size_t ob = ((size_t)((row >> 10) * HH + h0 + p) * TT + (row & 1023)) * HDIM + d1;
                        outp[ob] = (f16)o1;
                        outp[ob + 64] = (f16)o2;
                    }
                }
        } else {
#pragma unroll
            for (int mf = 0; mf < 8; mf++)
#pragma unroll
                for (int r = 0; r < 4; r++) {
                    int row = (bm << 8) + wm * 128 + mf * 16 + (quad << 2) + r;
                    float ve = __expf(cs[row]);
#pragma unroll
                    for (int nf = 0; nf < 4; nf++) {
                        int d = ((nf & 1) << 6) + d1;
                        size_t ob = ((size_t)((row >> 10) * HH + h0 + (nf >> 1)) * TT + (row & 1023)) * HDIM + d;
                        vsc[ob] = (f16)(acc[mf][nf][r] * ve);
                    }
                }
        }
    }
}

// ---------------- causal flash attention, S^T formulation ----------------
__global__ __launch_bounds__(256) void k_attn(const f16* __restrict__ qr,
                                              const f16* __restrict__ kr,
                                              const f16* __restrict__ vt,
                                              const float* __restrict__ pb,
                                              f16* __restrict__ y) {
    __shared__ __align__(16) f16 Ks[64 * 136];   // [kv][hd], pad 128->136
    __shared__ __align__(16) f16 Vs[128 * 72];   // [hd][kv], pad 64->72
    __shared__ float pbs[64];
    int p = blockIdx.x & (NQT / 2 - 1);
    int bh = blockIdx.x >> 3;
    int b = bh >> 4, h = bh & 15;
    int tid = threadIdx.x;
    int w = tid >> 6, lane = tid & 63, quad = lane >> 4, l16 = lane & 15;
#pragma unroll
    for (int pass = 0; pass < 2; pass++) {
        int qt = pass ? (NQT - 1 - p) : p;
        int q0 = qt << 6;
        int qg = q0 + w * 16 + l16;                  // this lane's q column
        const f16* Qp = qr + ((size_t)bh * TT + qg) * HDIM;
        half8 qf[4];                                  // B-op: Q[q=l16][hd=kc*32+quad*8+e]
#pragma unroll
        for (int kc = 0; kc < 4; kc++) qf[kc] = *(const half8*)&Qp[kc * 32 + (quad << 3)];
        floatx4 O[8];                                 // O^T[hd][q] C-frags
#pragma unroll
        for (int i = 0; i < 8; i++) O[i] = (floatx4){0.f, 0.f, 0.f, 0.f};
        float mx = -1e30f, ls = 0.f;
        for (int kt = 0; kt <= qt; kt++) {
            __syncthreads();
            const f16* Kb = kr + ((size_t)bh * TT + (kt << 6)) * HDIM;
            const f16* Vb = vt + (size_t)bh * HDIM * TT + (kt << 6);
#pragma unroll
            for (int i = 0; i < 4; i++) {
                int seg = tid + (i << 8);
                int krow = seg >> 4, kcol = (seg & 15) << 3;
                *(uint4*)&Ks[krow * 136 + kcol] = *(const uint4*)&Kb[(size_t)krow * HDIM + kcol];
                int vrow = seg >> 3, vcol = (seg & 7) << 3;
                *(uint4*)&Vs[vrow * 72 + vcol] = *(const uint4*)&Vb[(size_t)vrow * TT + vcol];
            }
            if (tid < 64) pbs[tid] = pb[b * TT + (kt << 6) + tid];
            __syncthreads();
            // S^T = K * Q^T : C-layout S^T[kv=quad*4+i][q=l16]
            floatx4 Sv[4];
#pragma unroll
            for (int mc = 0; mc < 4; mc++) Sv[mc] = (floatx4){0.f, 0.f, 0.f, 0.f};
#pragma unroll
            for (int kc = 0; kc < 4; kc++)
#pragma unroll
                for (int mc = 0; mc < 4; mc++) {
                    half8 kf = *(const half8*)&Ks[(mc * 16 + l16) * 136 + kc * 32 + (quad << 3)];
                    Sv[mc] = __builtin_amdgcn_mfma_f32_16x16x32_f16(kf, qf[kc], Sv[mc], 0, 0, 0);
                }
            // mask + bias + online softmax (per q column = per lane)
            float pv[4][4];
            float mnew = mx;
#pragma unroll
            for (int mc = 0; mc < 4; mc++) {
                float4 pbv = *(const float4*)&pbs[mc * 16 + (quad << 2)];
#pragma unroll
                for (int i = 0; i < 4; i++) {
                    int kv = (kt << 6) + mc * 16 + (quad << 2) + i;
                    float s = (kv <= qg) ? Sv[mc][i] + ((const float*)&pbv)[i] : -1e30f;
                    pv[mc][i] = s;
                    mnew = fmaxf(mnew, s);
                }
            }
            mnew = fmaxf(mnew, __shfl_xor(mnew, 16));
            mnew = fmaxf(mnew, __shfl_xor(mnew, 32));
            float al = __expf(mx - mnew);
            mx = mnew;
            float psum = 0.f;
#pragma unroll
            for (int mc = 0; mc < 4; mc++)
#pragma unroll
                for (int i = 0; i < 4; i++) {
                    float e = __expf(pv[mc][i] - mnew);
                    pv[mc][i] = e;
                    psum += e;
                }
            psum += __shfl_xor(psum, 16);
            psum += __shfl_xor(psum, 32);
            ls = ls * al + psum;
#pragma unroll
            for (int hm = 0; hm < 8; hm++)
#pragma unroll
                for (int i = 0; i < 4; i++) O[hm][i] *= al;
            // P^T as B-operand of 16x16x16 (k=quad*4+i == C rows). A = V^T.
            half4 pf[4];
#pragma unroll
            for (int mc = 0; mc < 4; mc++) {
                pf[mc][0] = (f16)pv[mc][0]; pf[mc][1] = (f16)pv[mc][1];
                pf[mc][2] = (f16)pv[mc][2]; pf[mc][3] = (f16)pv[mc][3];
            }
#pragma unroll
            for (int mc = 0; mc < 4; mc++)
#pragma unroll
                for (int hm = 0; hm < 8; hm++) {
                    half4 vf = *(const half4*)&Vs[(hm * 16 + l16) * 72 + mc * 16 + (quad << 2)];
                    O[hm] = __builtin_amdgcn_mfma_f32_16x16x16f16(vf, pf[mc], O[hm], 0, 0, 0);
                }
        }
        float inv = 1.0f / ls;
#pragma unroll
        for (int hm = 0; hm < 8; hm++) {
            half4 ov;
#pragma unroll
            for (int i = 0; i < 4; i++) ov[i] = (f16)(O[hm][i] * inv);
            *(half4*)&y[((size_t)b * TT + qg) * CCH + h * HDIM + hm * 16 + (quad << 2)] = ov;
        }
        __syncthreads();   // protect LDS before next pass restages
    }
}

extern "C" void kernel_launch(void* const* d_in, const int* in_sizes, int n_in,
                              void* d_out, int out_size, void* d_ws, size_t ws_size,
                              hipStream_t stream) {
    const float* x   = (const float*)d_in[0];
    const float* cs  = (const float*)d_in[1];
    const int*   tok = (const int*)d_in[2];
    const int*   pm  = (const int*)d_in[3];
    const float* Wa  = (const float*)d_in[4];
    const float* Wp  = (const float*)d_in[5];
    float* out = (float*)d_out;
    char* ws = (char*)d_ws;

    f16* x16 = (f16*)(ws + 0);             // 16 MB ; reused as y after GEMM1
    f16* WaT = (f16*)(ws + 16777216);      // 24 MB
    f16* vt  = (f16*)(ws + 41943040);      // 16 MB   [bh][hd][t]
    f16* WpT = (f16*)(ws + 58720256);      //  8 MB
    float2* tab = (float2*)(ws + 67108864);// 2 MB rope table (gap before qr)
    f16* qr  = (f16*)(ws + 92274688);      // 16 MB
    f16* kr  = (f16*)(ws + 109051904);     // 16 MB
    f16* vsc = (f16*)(ws + 125829120);     // 16 MB
    int*   cnt  = (int*)(ws + 142606336);  // 4 KB
    float* tpos = (float*)(ws + 142610432);// 16 KB
    float* pb   = (float*)(ws + 142626816);// 16 KB
    f16* y   = x16;

    hipMemsetAsync(cnt, 0, NBLK * sizeof(int), stream);
    k_hist<<<MM / 256, 256, 0, stream>>>(tok, cnt);
    k_scan<<<BB, TT, 0, stream>>>(tok, cnt, pm, tpos, pb);
    k_rope<<<MM * 64 / 256, 256, 0, stream>>>(tpos, tab);
    k_prep<<<dim3(N1 / 32, CCH / 32, 3), dim3(32, 8), 0, stream>>>(Wa, Wp, x, WaT, WpT, x16);
    k_gemm8<1><<<384, 512, 0, stream>>>(x16, WaT, nullptr, tab, cs, qr, kr, vsc);
    k_trv<<<dim3(4, 32, BB * HH), dim3(32, 8), 0, stream>>>(vsc, vt);
    k_attn<<<BB * HH * (NQT / 2), 256, 0, stream>>>(qr, kr, vt, pb, y);
    k_gemm8<0><<<128, 512, 0, stream>>>(y, WpT, out, nullptr, nullptr, nullptr, nullptr, nullptr);
}

// Round 4
// 421.061 us; speedup vs baseline: 1.0788x; 1.0788x over previous
//
#include <hip/hip_runtime.h>

#define BB 4
#define TT 1024
#define CCH 2048
#define HH 16
#define HDIM 128
#define NBLK 1024
#define MM (BB*TT)          // 4096
#define N1 (3*CCH)          // 6144
#define NQT 16              // T / 64

typedef _Float16 f16;
typedef _Float16 half8 __attribute__((ext_vector_type(8)));
typedef _Float16 half4 __attribute__((ext_vector_type(4)));
typedef float floatx4 __attribute__((ext_vector_type(4)));

// async global->LDS, 16B per lane. LDS dest = wave-uniform base + lane*16.
__device__ __forceinline__ void g2lds16(const void* g, void* l) {
    __builtin_amdgcn_global_load_lds((const __attribute__((address_space(1))) void*)g,
                                     (__attribute__((address_space(3))) void*)l, 16, 0, 0);
}

// ---- fused prep: z=0 transpose Wa -> WaT f16, z=1 Wp -> WpT, z=2 cvt x -> f16 ----
__global__ void k_prep(const float* __restrict__ Wa, const float* __restrict__ Wp,
                       const float* __restrict__ x,
                       f16* __restrict__ WaT, f16* __restrict__ WpT,
                       f16* __restrict__ x16) {
    int z = blockIdx.z;
    if (z == 2) {   // convert: MM*CCH/4 float4s
        int i = (blockIdx.y * 192 + blockIdx.x) * 256 + threadIdx.x + threadIdx.y * 32;
        if (i >= MM * CCH / 4) return;
        float4 v = ((const float4*)x)[i];
        union { ushort4 u; f16 h[4]; } o;
        o.h[0] = (f16)v.x; o.h[1] = (f16)v.y; o.h[2] = (f16)v.z; o.h[3] = (f16)v.w;
        ((ushort4*)x16)[i] = o.u;
        return;
    }
    const float* in = (z == 0) ? Wa : Wp;
    f16* out = (z == 0) ? WaT : WpT;
    int Cc = (z == 0) ? N1 : CCH;
    if (blockIdx.x * 32 >= Cc) return;
    __shared__ float tile[32][33];
    int c0 = blockIdx.x * 32, r0 = blockIdx.y * 32;
    int tx = threadIdx.x, ty = threadIdx.y;
#pragma unroll
    for (int k = 0; k < 4; k++) {
        int r = ty + k * 8;
        tile[r][tx] = in[(size_t)(r0 + r) * Cc + c0 + tx];
    }
    __syncthreads();
#pragma unroll
    for (int k = 0; k < 4; k++) {
        int r = ty + k * 8;
        out[(size_t)(c0 + r) * CCH + r0 + tx] = (f16)tile[tx][r];
    }
}

// ------- transpose f16 per-head [T][HD] -> [HD][T] (for V) -------
__global__ void k_trv(const f16* __restrict__ in, f16* __restrict__ out) {
    __shared__ f16 tile[32][34];
    int bh = blockIdx.z;
    int h0 = blockIdx.x * 32, t0 = blockIdx.y * 32;
    int tx = threadIdx.x, ty = threadIdx.y;
#pragma unroll
    for (int k = 0; k < 4; k++) {
        int t = ty + k * 8;
        tile[t][tx] = in[((size_t)bh * TT + t0 + t) * HDIM + h0 + tx];
    }
    __syncthreads();
#pragma unroll
    for (int k = 0; k < 4; k++) {
        int r = ty + k * 8;
        out[((size_t)bh * HDIM + h0 + r) * TT + t0 + tx] = tile[tx][r];
    }
}

// ---------------- global histogram over all B*T tokens ----------------
__global__ void k_hist(const int* __restrict__ tok, int* __restrict__ cnt) {
    int i = blockIdx.x * blockDim.x + threadIdx.x;
    if (i < MM) atomicAdd(cnt + tok[i], 1);
}

// ------- per-batch inclusive scan of 1/count; also padding bias -------
__global__ __launch_bounds__(1024) void k_scan(const int* __restrict__ tok,
                                               const int* __restrict__ cnt,
                                               const int* __restrict__ pm,
                                               float* __restrict__ tpos,
                                               float* __restrict__ pb) {
    __shared__ float s[TT];
    int b = blockIdx.x, t = threadIdx.x;
    s[t] = 1.0f / ((float)cnt[tok[b * TT + t]] + 1e-10f);
    __syncthreads();
    for (int off = 1; off < TT; off <<= 1) {
        float add = (t >= off) ? s[t - off] : 0.0f;
        __syncthreads();
        s[t] += add;
        __syncthreads();
    }
    tpos[b * TT + t] = s[t];
    pb[b * TT + t] = pm[b * TT + t] ? 0.0f : -1e30f;
}

// ------- rope table: tab[row*64+j] = (cos, sin) of tpos[row]*10000^(-j/64) -------
__global__ void k_rope(const float* __restrict__ tpos, float2* __restrict__ tab) {
    int i = blockIdx.x * 256 + threadIdx.x;     // MM*64 entries
    int row = i >> 6, j = i & 63;
    float f = tpos[row] * expf((float)j * -0.14391156929f);   // ln(10000)/64
    float sn, cn; sincosf(f, &sn, &cn);
    tab[i] = make_float2(cn, sn);
}

// ================= 256x256 8-phase GEMM (BK=64, 8 waves, dbuf LDS) =================
// A[M][2048] f16, Bt[N][2048] f16. Per-wave 128x64 output (acc[8][4] floatx4).
// T2 (v2): CHUNK-ROTATION swizzle. LDS tile [256 rows][64 f16] (128B rows, 8
//   16B-chunks/row). LDS[r][c] holds global chunk (c - r) & 7; reads fetch
//   chunk (g + r) & 7. Any 16 consecutive lanes of a ds_read_b128 (fixed quad,
//   l16=0..15) rotate through all 8 chunk positions -> 2 lanes/position = free
//   (m136: 2-way = 1.02x). Round-1's XOR left only 4 positions -> 8-way, 9.4M
//   conflict cycles. Write side: linear global_load_lds dest + inverse-rotated
//   per-lane GLOBAL source (rule 21); per-row source union is a contiguous
//   128B segment, so coalescing is unchanged.
// T3/T4: 8 phases/iter (2 K-tiles), 1 half-tile staged per phase, counted
//   s_waitcnt vmcnt(6) ONLY at phases 4 and 8 (raw s_barrier everywhere).
// T5: setprio(1) around each 16-MFMA cluster.
#define RA(buf, mf, ck) (*(const half8*)((const char*)As + ((buf) << 15) + aoffb + ((mf) << 11) + (ck)))
#define RB(buf, nf, ck) (*(const half8*)((const char*)Bs + ((buf) << 15) + boffb + ((nf) << 13) + (ck)))
#define STAGE(P, L, h, t) do { \
    g2lds16((P) + ((size_t)(h) << 18) + ((t) << 6) + src0, (L) + ((h) << 13) + (w << 9)); \
    g2lds16((P) + ((size_t)(h) << 18) + ((t) << 6) + src1, (L) + ((h) << 13) + ((8 + w) << 9)); \
} while (0)
#define MFMAQ(AF, BF, M0, N0) do { \
  _Pragma("unroll") for (int m_ = 0; m_ < 4; m_++) \
  _Pragma("unroll") for (int n_ = 0; n_ < 2; n_++) \
  _Pragma("unroll") for (int k_ = 0; k_ < 2; k_++) \
    acc[(M0) + m_][(N0) + n_] = __builtin_amdgcn_mfma_f32_16x16x32_f16(AF[m_][k_], BF[n_][k_], acc[(M0) + m_][(N0) + n_], 0, 0, 0); \
} while (0)
#define BAR() __builtin_amdgcn_s_barrier()
#define WLG0() asm volatile("s_waitcnt lgkmcnt(0)" ::: "memory")

template <int MODE>   // 1: QKV fused rope epilogue (N=6144); 0: plain f32 C (N=2048)
__global__ __launch_bounds__(512, 2) void k_gemm8(const f16* __restrict__ A,
                                                  const f16* __restrict__ Bt,
                                                  float* __restrict__ Cp,
                                                  const float2* __restrict__ tab,
                                                  const float* __restrict__ cs,
                                                  f16* __restrict__ qr,
                                                  f16* __restrict__ kr,
                                                  f16* __restrict__ vsc) {
    const float SCALE = 0.08838834764831845f;   // 1/sqrt(128), folded into q
    const int NBN = MODE ? 24 : 8;
    const int NWG = MODE ? 384 : 128;
    const int CPX = NWG >> 3;
    __shared__ __align__(16) f16 As[2 * 16384];   // [buf][256][64], 64KB
    __shared__ __align__(16) f16 Bs[2 * 16384];   // [buf][256][64], 64KB

    int bid = blockIdx.x;
    int s = (bid & 7) * CPX + (bid >> 3);          // XCD-aware swizzle (bijective: NWG%8==0)
    int bm = s / NBN, bn = s % NBN;

    int tid = threadIdx.x;
    int w = tid >> 6, lane = tid & 63, quad = lane >> 4, l16 = lane & 15;
    int wm = w >> 2, wn = w & 3;                   // 2 x 4 wave grid

    const f16* Ab = A + (size_t)(bm << 8) * 2048;
    const f16* Bb = Bt + (size_t)(bn << 8) * 2048;

    // staging source offsets: lane covers (row = w*8 + lane>>3, chunk c = lane&7);
    // source chunk g = (c - row) & 7 so a linear LDS write lands rotation-swizzled.
    int rl = lane >> 3, cl = lane & 7;
    int gl = (cl - rl) & 7;
    int src0 = (w * 8 + rl) * 2048 + gl * 8;       // f16 elements within tile panel
    int src1 = src0 + 64 * 2048;                   // +64 rows

    // frag-read bases; chunk constants: read chunk (g + row) & 7, row&7 == l16&7,
    // g = kk*4 + quad  ->  ck0 = ((quad + l16) & 7) * 16 bytes, ck1 = ck0 ^ 64.
    const int aoffb = (wm * 128 + l16) << 7;
    const int boffb = (wn * 16 + l16) << 7;
    const int ck0 = ((quad + l16) & 7) << 4;
    const int ck1 = ck0 ^ 64;

    floatx4 acc[8][4];
#pragma unroll
    for (int i = 0; i < 8; i++)
#pragma unroll
        for (int j = 0; j < 4; j++) acc[i][j] = (floatx4){0.f, 0.f, 0.f, 0.f};

    // ---- prologue: tile0 (4 halves) + tile1 (Bh0,Ah0,Ah1); Bh1(1) comes in ph1
    STAGE(Bb, Bs, 0, 0);
    STAGE(Ab, As, 0, 0);
    STAGE(Ab, As, 1, 0);
    STAGE(Bb, Bs, 1, 0);
    STAGE(Bb, Bs + 16384, 0, 1);
    STAGE(Ab, As + 16384, 0, 1);
    STAGE(Ab, As + 16384, 1, 1);
    asm volatile("s_waitcnt vmcnt(6)" ::: "memory");   // tile0 fully landed
    BAR();

#pragma unroll 1
    for (int it = 0; it < 16; ++it) {
        const int t1 = 2 * it + 1, t2 = 2 * it + 2, t3 = 2 * it + 3;
        const bool g2 = (t2 < 32), g3 = (t3 < 32);
        half8 af0[4][2], af1[4][2], bf0[2][2], bf1[2][2];
        // ---- phase 1 (buf0): reads A.mh0(8) + B.nh0(4); stage Bh1(t1)->buf1
#pragma unroll
        for (int m = 0; m < 4; m++) { af0[m][0] = RA(0, m, ck0); af0[m][1] = RA(0, m, ck1); }
#pragma unroll
        for (int n = 0; n < 2; n++) { bf0[n][0] = RB(0, n, ck0); bf0[n][1] = RB(0, n, ck1); }
        STAGE(Bb, Bs + 16384, 1, t1);
        asm volatile("s_waitcnt lgkmcnt(8)" ::: "memory");
        BAR(); WLG0();
        __builtin_amdgcn_s_setprio(1); MFMAQ(af0, bf0, 0, 0); __builtin_amdgcn_s_setprio(0);
        BAR();
        // ---- phase 2: reads A.mh1(8); stage Bh0(t2)->buf0
#pragma unroll
        for (int m = 0; m < 4; m++) { af1[m][0] = RA(0, 4 + m, ck0); af1[m][1] = RA(0, 4 + m, ck1); }
        if (g2) STAGE(Bb, Bs, 0, t2);
        BAR(); WLG0();
        __builtin_amdgcn_s_setprio(1); MFMAQ(af1, bf0, 4, 0); __builtin_amdgcn_s_setprio(0);
        BAR();
        // ---- phase 3: reads B.nh1(4); stage Ah0(t2)->buf0
#pragma unroll
        for (int n = 0; n < 2; n++) { bf1[n][0] = RB(0, 2 + n, ck0); bf1[n][1] = RB(0, 2 + n, ck1); }
        if (g2) STAGE(Ab, As, 0, t2);
        BAR(); WLG0();
        __builtin_amdgcn_s_setprio(1); MFMAQ(af1, bf1, 4, 2); __builtin_amdgcn_s_setprio(0);
        BAR();
        // ---- phase 4: stage Ah1(t2)->buf0; counted vmcnt (tile t1 now complete)
        if (g2) STAGE(Ab, As, 1, t2);
        BAR();
        __builtin_amdgcn_s_setprio(1); MFMAQ(af0, bf1, 0, 2); __builtin_amdgcn_s_setprio(0);
        if (it < 15) { asm volatile("s_waitcnt vmcnt(6)" ::: "memory"); }
        else         { asm volatile("s_waitcnt vmcnt(0)" ::: "memory"); }
        BAR();
        // ---- phase 5 (buf1): reads; stage Bh1(t2)->buf0
#pragma unroll
        for (int m = 0; m < 4; m++) { af0[m][0] = RA(1, m, ck0); af0[m][1] = RA(1, m, ck1); }
#pragma unroll
        for (int n = 0; n < 2; n++) { bf0[n][0] = RB(1, n, ck0); bf0[n][1] = RB(1, n, ck1); }
        if (g2) STAGE(Bb, Bs, 1, t2);
        asm volatile("s_waitcnt lgkmcnt(8)" ::: "memory");
        BAR(); WLG0();
        __builtin_amdgcn_s_setprio(1); MFMAQ(af0, bf0, 0, 0); __builtin_amdgcn_s_setprio(0);
        BAR();
        // ---- phase 6: stage Bh0(t3)->buf1
#pragma unroll
        for (int m = 0; m < 4; m++) { af1[m][0] = RA(1, 4 + m, ck0); af1[m][1] = RA(1, 4 + m, ck1); }
        if (g3) STAGE(Bb, Bs + 16384, 0, t3);
        BAR(); WLG0();
        __builtin_amdgcn_s_setprio(1); MFMAQ(af1, bf0, 4, 0); __builtin_amdgcn_s_setprio(0);
        BAR();
        // ---- phase 7: stage Ah0(t3)->buf1
#pragma unroll
        for (int n = 0; n < 2; n++) { bf1[n][0] = RB(1, 2 + n, ck0); bf1[n][1] = RB(1, 2 + n, ck1); }
        if (g3) STAGE(Ab, As + 16384, 0, t3);
        BAR(); WLG0();
        __builtin_amdgcn_s_setprio(1); MFMAQ(af1, bf1, 4, 2); __builtin_amdgcn_s_setprio(0);
        BAR();
        // ---- phase 8: stage Ah1(t3)->buf1; counted vmcnt (tile t2 complete)
        if (g3) STAGE(Ab, As + 16384, 1, t3);
        BAR();
        __builtin_amdgcn_s_setprio(1); MFMAQ(af0, bf1, 0, 2); __builtin_amdgcn_s_setprio(0);
        if (it < 15) { asm volatile("s_waitcnt vmcnt(6)" ::: "memory"); }
        else         { asm volatile("s_waitcnt vmcnt(0)" ::: "memory"); }
        BAR();
    }

    // ---- epilogue: rows = bm*256 + wm*128 + mf*16 + quad*4 + r
    //      cols = bn*256 + wn*16 + nf*64 + l16
    if (MODE == 0) {
#pragma unroll
        for (int mf = 0; mf < 8; mf++)
#pragma unroll
            for (int nf = 0; nf < 4; nf++) {
                int col = (bn << 8) + wn * 16 + nf * 64 + l16;
#pragma unroll
                for (int r = 0; r < 4; r++) {
                    int row = (bm << 8) + wm * 128 + mf * 16 + (quad << 2) + r;
                    Cp[(size_t)row * CCH + col] = acc[mf][nf][r];
                }
            }
    } else {
        int type = bn >> 3;              // 0=q, 1=k, 2=v (8 blocks per 2048-col chunk)
        int h0 = (bn * 2) & 15;          // first of the block's 2 heads
        int d1 = wn * 16 + l16;          // 0..63 (low half of head dim)
        if (type < 2) {
            f16* outp = (type == 0) ? qr : kr;
#pragma unroll
            for (int mf = 0; mf < 8; mf++)
#pragma unroll
                for (int r = 0; r < 4; r++) {
                    int row = (bm << 8) + wm * 128 + mf * 16 + (quad << 2) + r;
                    float2 tc = tab[row * 64 + d1];
#pragma unroll
                    for (int p = 0; p < 2; p++) {     // head pair: nf {0,1} and {2,3}
                        float a1 = acc[mf][2 * p][r], a2 = acc[mf][2 * p + 1][r];
                        float o1 = a1 * tc.x - a2 * tc.y;
                        float o2 = a2 * tc.x + a1 * tc.y;
                        if (type == 0) {
                            if (d1 == 63) o2 = 1.0f;          // q[...,-1]=1 (before scale)
                            o1 *= SCALE; o2 *= SCALE;
                        } else {
                            if (d1 == 63) o2 = cs[row];       // k[...,-1]=cum_scores
                        }
                        size_t ob = ((size_t)((row >> 10) * HH + h0 + p) * TT + (row & 1023)) * HDIM + d1;
                        outp[ob] = (f16)o1;
                        outp[ob + 64] = (f16)o2;
                    }
                }
        } else {
#pragma unroll
            for (int mf = 0; mf < 8; mf++)
#pragma unroll
                for (int r = 0; r < 4; r++) {
                    int row = (bm << 8) + wm * 128 + mf * 16 + (quad << 2) + r;
                    float ve = __expf(cs[row]);
#pragma unroll
                    for (int nf = 0; nf < 4; nf++) {
                        int d = ((nf & 1) << 6) + d1;
                        size_t ob = ((size_t)((row >> 10) * HH + h0 + (nf >> 1)) * TT + (row & 1023)) * HDIM + d;
                        vsc[ob] = (f16)(acc[mf][nf][r] * ve);
                    }
                }
        }
    }
}

// ---------------- causal flash attention, S^T formulation ----------------
__global__ __launch_bounds__(256) void k_attn(const f16* __restrict__ qr,
                                              const f16* __restrict__ kr,
                                              const f16* __restrict__ vt,
                                              const float* __restrict__ pb,
                                              f16* __restrict__ y) {
    __shared__ __align__(16) f16 Ks[64 * 136];   // [kv][hd], pad 128->136
    __shared__ __align__(16) f16 Vs[128 * 72];   // [hd][kv], pad 64->72
    __shared__ float pbs[64];
    int p = blockIdx.x & (NQT / 2 - 1);
    int bh = blockIdx.x >> 3;
    int b = bh >> 4, h = bh & 15;
    int tid = threadIdx.x;
    int w = tid >> 6, lane = tid & 63, quad = lane >> 4, l16 = lane & 15;
#pragma unroll
    for (int pass = 0; pass < 2; pass++) {
        int qt = pass ? (NQT - 1 - p) : p;
        int q0 = qt << 6;
        int qg = q0 + w * 16 + l16;                  // this lane's q column
        const f16* Qp = qr + ((size_t)bh * TT + qg) * HDIM;
        half8 qf[4];                                  // B-op: Q[q=l16][hd=kc*32+quad*8+e]
#pragma unroll
        for (int kc = 0; kc < 4; kc++) qf[kc] = *(const half8*)&Qp[kc * 32 + (quad << 3)];
        floatx4 O[8];                                 // O^T[hd][q] C-frags
#pragma unroll
        for (int i = 0; i < 8; i++) O[i] = (floatx4){0.f, 0.f, 0.f, 0.f};
        float mx = -1e30f, ls = 0.f;
        for (int kt = 0; kt <= qt; kt++) {
            __syncthreads();
            const f16* Kb = kr + ((size_t)bh * TT + (kt << 6)) * HDIM;
            const f16* Vb = vt + (size_t)bh * HDIM * TT + (kt << 6);
#pragma unroll
            for (int i = 0; i < 4; i++) {
                int seg = tid + (i << 8);
                int krow = seg >> 4, kcol = (seg & 15) << 3;
                *(uint4*)&Ks[krow * 136 + kcol] = *(const uint4*)&Kb[(size_t)krow * HDIM + kcol];
                int vrow = seg >> 3, vcol = (seg & 7) << 3;
                *(uint4*)&Vs[vrow * 72 + vcol] = *(const uint4*)&Vb[(size_t)vrow * TT + vcol];
            }
            if (tid < 64) pbs[tid] = pb[b * TT + (kt << 6) + tid];
            __syncthreads();
            // S^T = K * Q^T : C-layout S^T[kv=quad*4+i][q=l16]
            floatx4 Sv[4];
#pragma unroll
            for (int mc = 0; mc < 4; mc++) Sv[mc] = (floatx4){0.f, 0.f, 0.f, 0.f};
#pragma unroll
            for (int kc = 0; kc < 4; kc++)
#pragma unroll
                for (int mc = 0; mc < 4; mc++) {
                    half8 kf = *(const half8*)&Ks[(mc * 16 + l16) * 136 + kc * 32 + (quad << 3)];
                    Sv[mc] = __builtin_amdgcn_mfma_f32_16x16x32_f16(kf, qf[kc], Sv[mc], 0, 0, 0);
                }
            // mask + bias + online softmax (per q column = per lane)
            float pv[4][4];
            float mnew = mx;
#pragma unroll
            for (int mc = 0; mc < 4; mc++) {
                float4 pbv = *(const float4*)&pbs[mc * 16 + (quad << 2)];
#pragma unroll
                for (int i = 0; i < 4; i++) {
                    int kv = (kt << 6) + mc * 16 + (quad << 2) + i;
                    float s = (kv <= qg) ? Sv[mc][i] + ((const float*)&pbv)[i] : -1e30f;
                    pv[mc][i] = s;
                    mnew = fmaxf(mnew, s);
                }
            }
            mnew = fmaxf(mnew, __shfl_xor(mnew, 16));
            mnew = fmaxf(mnew, __shfl_xor(mnew, 32));
            float al = __expf(mx - mnew);
            mx = mnew;
            float psum = 0.f;
#pragma unroll
            for (int mc = 0; mc < 4; mc++)
#pragma unroll
                for (int i = 0; i < 4; i++) {
                    float e = __expf(pv[mc][i] - mnew);
                    pv[mc][i] = e;
                    psum += e;
                }
            psum += __shfl_xor(psum, 16);
            psum += __shfl_xor(psum, 32);
            ls = ls * al + psum;
#pragma unroll
            for (int hm = 0; hm < 8; hm++)
#pragma unroll
                for (int i = 0; i < 4; i++) O[hm][i] *= al;
            // P^T as B-operand of 16x16x16 (k=quad*4+i == C rows). A = V^T.
            half4 pf[4];
#pragma unroll
            for (int mc = 0; mc < 4; mc++) {
                pf[mc][0] = (f16)pv[mc][0]; pf[mc][1] = (f16)pv[mc][1];
                pf[mc][2] = (f16)pv[mc][2]; pf[mc][3] = (f16)pv[mc][3];
            }
#pragma unroll
            for (int mc = 0; mc < 4; mc++)
#pragma unroll
                for (int hm = 0; hm < 8; hm++) {
                    half4 vf = *(const half4*)&Vs[(hm * 16 + l16) * 72 + mc * 16 + (quad << 2)];
                    O[hm] = __builtin_amdgcn_mfma_f32_16x16x16f16(vf, pf[mc], O[hm], 0, 0, 0);
                }
        }
        float inv = 1.0f / ls;
#pragma unroll
        for (int hm = 0; hm < 8; hm++) {
            half4 ov;
#pragma unroll
            for (int i = 0; i < 4; i++) ov[i] = (f16)(O[hm][i] * inv);
            *(half4*)&y[((size_t)b * TT + qg) * CCH + h * HDIM + hm * 16 + (quad << 2)] = ov;
        }
        __syncthreads();   // protect LDS before next pass restages
    }
}

extern "C" void kernel_launch(void* const* d_in, const int* in_sizes, int n_in,
                              void* d_out, int out_size, void* d_ws, size_t ws_size,
                              hipStream_t stream) {
    const float* x   = (const float*)d_in[0];
    const float* cs  = (const float*)d_in[1];
    const int*   tok = (const int*)d_in[2];
    const int*   pm  = (const int*)d_in[3];
    const float* Wa  = (const float*)d_in[4];
    const float* Wp  = (const float*)d_in[5];
    float* out = (float*)d_out;
    char* ws = (char*)d_ws;

    f16* x16 = (f16*)(ws + 0);             // 16 MB ; reused as y after GEMM1
    f16* WaT = (f16*)(ws + 16777216);      // 24 MB
    f16* vt  = (f16*)(ws + 41943040);      // 16 MB   [bh][hd][t]
    f16* WpT = (f16*)(ws + 58720256);      //  8 MB
    float2* tab = (float2*)(ws + 67108864);// 2 MB rope table (gap before qr)
    f16* qr  = (f16*)(ws + 92274688);      // 16 MB
    f16* kr  = (f16*)(ws + 109051904);     // 16 MB
    f16* vsc = (f16*)(ws + 125829120);     // 16 MB
    int*   cnt  = (int*)(ws + 142606336);  // 4 KB
    float* tpos = (float*)(ws + 142610432);// 16 KB
    float* pb   = (float*)(ws + 142626816);// 16 KB
    f16* y   = x16;

    hipMemsetAsync(cnt, 0, NBLK * sizeof(int), stream);
    k_hist<<<MM / 256, 256, 0, stream>>>(tok, cnt);
    k_scan<<<BB, TT, 0, stream>>>(tok, cnt, pm, tpos, pb);
    k_rope<<<MM * 64 / 256, 256, 0, stream>>>(tpos, tab);
    k_prep<<<dim3(N1 / 32, CCH / 32, 3), dim3(32, 8), 0, stream>>>(Wa, Wp, x, WaT, WpT, x16);
    k_gemm8<1><<<384, 512, 0, stream>>>(x16, WaT, nullptr, tab, cs, qr, kr, vsc);
    k_trv<<<dim3(4, 32, BB * HH), dim3(32, 8), 0, stream>>>(vsc, vt);
    k_attn<<<BB * HH * (NQT / 2), 256, 0, stream>>>(qr, kr, vt, pb, y);
    k_gemm8<0><<<128, 512, 0, stream>>>(y, WpT, out, nullptr, nullptr, nullptr, nullptr, nullptr);
}

// Round 5
// 384.968 us; speedup vs baseline: 1.1800x; 1.0938x over previous
//
#include <hip/hip_runtime.h>

#define BB 4
#define TT 1024
#define CCH 2048
#define HH 16
#define HDIM 128
#define NBLK 1024
#define MM (BB*TT)          // 4096
#define N1 (3*CCH)          // 6144
#define NQT 16              // T / 64

typedef _Float16 f16;
typedef _Float16 half8 __attribute__((ext_vector_type(8)));
typedef _Float16 half4 __attribute__((ext_vector_type(4)));
typedef float floatx4 __attribute__((ext_vector_type(4)));

// async global->LDS, 16B per lane. LDS dest = wave-uniform base + lane*16.
__device__ __forceinline__ void g2lds16(const void* g, void* l) {
    __builtin_amdgcn_global_load_lds((const __attribute__((address_space(1))) void*)g,
                                     (__attribute__((address_space(3))) void*)l, 16, 0, 0);
}

// ---- fused prep: z=0 transpose Wa -> WaT f16, z=1 Wp -> WpT, z=2 cvt x -> f16 ----
__global__ void k_prep(const float* __restrict__ Wa, const float* __restrict__ Wp,
                       const float* __restrict__ x,
                       f16* __restrict__ WaT, f16* __restrict__ WpT,
                       f16* __restrict__ x16) {
    int z = blockIdx.z;
    if (z == 2) {   // convert: MM*CCH/4 float4s
        int i = (blockIdx.y * 192 + blockIdx.x) * 256 + threadIdx.x + threadIdx.y * 32;
        if (i >= MM * CCH / 4) return;
        float4 v = ((const float4*)x)[i];
        union { ushort4 u; f16 h[4]; } o;
        o.h[0] = (f16)v.x; o.h[1] = (f16)v.y; o.h[2] = (f16)v.z; o.h[3] = (f16)v.w;
        ((ushort4*)x16)[i] = o.u;
        return;
    }
    const float* in = (z == 0) ? Wa : Wp;
    f16* out = (z == 0) ? WaT : WpT;
    int Cc = (z == 0) ? N1 : CCH;
    if (blockIdx.x * 32 >= Cc) return;
    __shared__ float tile[32][33];
    int c0 = blockIdx.x * 32, r0 = blockIdx.y * 32;
    int tx = threadIdx.x, ty = threadIdx.y;
#pragma unroll
    for (int k = 0; k < 4; k++) {
        int r = ty + k * 8;
        tile[r][tx] = in[(size_t)(r0 + r) * Cc + c0 + tx];
    }
    __syncthreads();
#pragma unroll
    for (int k = 0; k < 4; k++) {
        int r = ty + k * 8;
        out[(size_t)(c0 + r) * CCH + r0 + tx] = (f16)tile[tx][r];
    }
}

// ------- transpose f16 per-head [T][HD] -> [HD][T] (for V) -------
__global__ void k_trv(const f16* __restrict__ in, f16* __restrict__ out) {
    __shared__ f16 tile[32][34];
    int bh = blockIdx.z;
    int h0 = blockIdx.x * 32, t0 = blockIdx.y * 32;
    int tx = threadIdx.x, ty = threadIdx.y;
#pragma unroll
    for (int k = 0; k < 4; k++) {
        int t = ty + k * 8;
        tile[t][tx] = in[((size_t)bh * TT + t0 + t) * HDIM + h0 + tx];
    }
    __syncthreads();
#pragma unroll
    for (int k = 0; k < 4; k++) {
        int r = ty + k * 8;
        out[((size_t)bh * HDIM + h0 + r) * TT + t0 + tx] = tile[tx][r];
    }
}

// ---------------- global histogram over all B*T tokens ----------------
__global__ void k_hist(const int* __restrict__ tok, int* __restrict__ cnt) {
    int i = blockIdx.x * blockDim.x + threadIdx.x;
    if (i < MM) atomicAdd(cnt + tok[i], 1);
}

// ------- per-batch inclusive scan of 1/count; also padding bias -------
__global__ __launch_bounds__(1024) void k_scan(const int* __restrict__ tok,
                                               const int* __restrict__ cnt,
                                               const int* __restrict__ pm,
                                               float* __restrict__ tpos,
                                               float* __restrict__ pb) {
    __shared__ float s[TT];
    int b = blockIdx.x, t = threadIdx.x;
    s[t] = 1.0f / ((float)cnt[tok[b * TT + t]] + 1e-10f);
    __syncthreads();
    for (int off = 1; off < TT; off <<= 1) {
        float add = (t >= off) ? s[t - off] : 0.0f;
        __syncthreads();
        s[t] += add;
        __syncthreads();
    }
    tpos[b * TT + t] = s[t];
    pb[b * TT + t] = pm[b * TT + t] ? 0.0f : -1e30f;
}

// ------- rope table: tab[row*64+j] = (cos, sin) of tpos[row]*10000^(-j/64) -------
__global__ void k_rope(const float* __restrict__ tpos, float2* __restrict__ tab) {
    int i = blockIdx.x * 256 + threadIdx.x;     // MM*64 entries
    int row = i >> 6, j = i & 63;
    float f = tpos[row] * expf((float)j * -0.14391156929f);   // ln(10000)/64
    float sn, cn; sincosf(f, &sn, &cn);
    tab[i] = make_float2(cn, sn);
}

// ============ 256x128 software-pipelined GEMM (BK=64, 8 waves, dbuf LDS) ============
// A[M][2048] f16, Bt[N][2048] f16. Per-wave 128x32 (acc[8][2]); B cols mapped
// wn*16 + nf*64 + l16 so rope pairs (d, d+64) stay in-wave.
// 4-phase loop over tile pairs (t@buf0, t+1@buf1), one 16-MFMA cluster/phase:
//   each phase ISSUES the next phase's 10 ds_read_b128 (into the alternate
//   frag set S0/S1) BEFORE its MFMA cluster -> LDS port (~625cy) drains under
//   the MFMA cluster (~620cy) instead of serializing (round-4 stall).
// Barriers: ONE per phase (4 per 2 K-tiles vs 16 before).
// Stage windows: stage(t+2)->buf0 in ph2 (buf0 fully prefetched by ph1's
// reads), waited vmcnt(0) at ph3-trail (>=1.3-phase flight); stage(t+3)->buf1
// in ph4, waited at next ph1-trail. Rotation swizzle (round 4, conflicts==0)
// kept verbatim: LDS[r][c] holds global chunk (c-r)&7 via pre-rotated source.
#define BAR() __builtin_amdgcn_s_barrier()
#define RDA(S, buf, ck) do { _Pragma("unroll") for (int m_ = 0; m_ < 8; m_++) \
    S[m_] = *(const half8*)((const char*)As + ((buf) << 15) + aoffb + (m_ << 11) + (ck)); } while (0)
#define RDB(S, buf, ck) do { _Pragma("unroll") for (int n_ = 0; n_ < 2; n_++) \
    S[n_] = *(const half8*)((const char*)Bs + ((buf) << 14) + boffb + (n_ << 13) + (ck)); } while (0)
#define STAGEA(t, lofs) do { _Pragma("unroll") for (int k_ = 0; k_ < 4; k_++) \
    g2lds16(Ab + (size_t)(k_ * 64) * 2048 + ((t) << 6) + srcr, \
            (char*)As + (lofs) + (w * 8 + k_ * 64) * 128); } while (0)
#define STAGEB(t, lofs) do { _Pragma("unroll") for (int k_ = 0; k_ < 2; k_++) \
    g2lds16(Bb + (size_t)(k_ * 64) * 2048 + ((t) << 6) + srcr, \
            (char*)Bs + (lofs) + (w * 8 + k_ * 64) * 128); } while (0)
#define MF16(SA, SB) do { _Pragma("unroll") for (int m_ = 0; m_ < 8; m_++) \
    _Pragma("unroll") for (int n_ = 0; n_ < 2; n_++) \
    acc[m_][n_] = __builtin_amdgcn_mfma_f32_16x16x32_f16(SA[m_], SB[n_], acc[m_][n_], 0, 0, 0); } while (0)

template <int MODE>   // 1: QKV fused rope epilogue (N=6144); 0: plain f32 C (N=2048)
__global__ __launch_bounds__(512, 2) void k_gemm8(const f16* __restrict__ A,
                                                  const f16* __restrict__ Bt,
                                                  float* __restrict__ Cp,
                                                  const float2* __restrict__ tab,
                                                  const float* __restrict__ cs,
                                                  f16* __restrict__ qr,
                                                  f16* __restrict__ kr,
                                                  f16* __restrict__ vsc) {
    const float SCALE = 0.08838834764831845f;   // 1/sqrt(128), folded into q
    const int NBN = MODE ? 48 : 16;
    const int NWG = MODE ? 768 : 256;
    const int CPX = NWG >> 3;
    __shared__ __align__(16) f16 As[2 * 16384];   // [buf][256][64], 64KB
    __shared__ __align__(16) f16 Bs[2 * 8192];    // [buf][128][64], 32KB

    int bid = blockIdx.x;
    int s = (bid & 7) * CPX + (bid >> 3);          // XCD swizzle (bijective: NWG%8==0)
    int bm = s / NBN, bn = s % NBN;

    int tid = threadIdx.x;
    int w = tid >> 6, lane = tid & 63, quad = lane >> 4, l16 = lane & 15;
    int wm = w >> 2, wn = w & 3;                   // 2 x 4 wave grid

    const f16* Ab = A + (size_t)(bm << 8) * 2048;
    const f16* Bb = Bt + (size_t)(bn << 7) * 2048;

    // rotation-swizzle staging source: lane = (row rl, chunk cl); source chunk
    // (cl - row)&7 (row-block offsets are ==0 mod 8, so gl is row-invariant).
    int rl = lane >> 3, cl = lane & 7;
    int gl = (cl - rl) & 7;
    int srcr = (w * 8 + rl) * 2048 + gl * 8;

    // frag-read bases; read chunk (g + row)&7, row&7 == l16&7, g = kk*4 + quad.
    const int aoffb = (wm * 128 + l16) << 7;
    const int boffb = (wn * 16 + l16) << 7;
    const int ck0 = ((quad + l16) & 7) << 4;
    const int ck1 = ck0 ^ 64;

    floatx4 acc[8][2];
#pragma unroll
    for (int i = 0; i < 8; i++)
#pragma unroll
        for (int j = 0; j < 2; j++) acc[i][j] = (floatx4){0.f, 0.f, 0.f, 0.f};

    half8 S0a[8], S1a[8];
    half8 S0b[2], S1b[2];

    // prologue: stage tile0 -> buf0 (6 loads), tile1 -> buf1 (6 loads)
    STAGEA(0, 0);      STAGEB(0, 0);
    STAGEA(1, 32768);  STAGEB(1, 16384);
    asm volatile("s_waitcnt vmcnt(6)" ::: "memory");   // tile0 landed (all waves + bar)
    BAR();
    RDA(S0a, 0, ck0); RDB(S0b, 0, ck0);                // tile0.kk0 -> S0

#pragma unroll 1
    for (int i = 0; i < 16; ++i) {
        const int t2 = 2 * i + 2, t3 = 2 * i + 3;
        // ph1: prefetch t.kk1 -> S1; compute t.kk0; wait stage(t+1); BAR
        RDA(S1a, 0, ck1); RDB(S1b, 0, ck1);
        __builtin_amdgcn_s_setprio(1); MF16(S0a, S0b); __builtin_amdgcn_s_setprio(0);
        asm volatile("s_waitcnt vmcnt(0)" ::: "memory");   // (t+1) landed
        BAR();
        // ph2: prefetch (t+1).kk0 -> S0; stage t+2 -> buf0; compute t.kk1; BAR
        RDA(S0a, 1, ck0); RDB(S0b, 1, ck0);
        if (t2 < 32) { STAGEA(t2, 0); STAGEB(t2, 0); }
        __builtin_amdgcn_s_setprio(1); MF16(S1a, S1b); __builtin_amdgcn_s_setprio(0);
        BAR();
        // ph3: prefetch (t+1).kk1 -> S1; compute (t+1).kk0; wait stage(t+2); BAR
        RDA(S1a, 1, ck1); RDB(S1b, 1, ck1);
        __builtin_amdgcn_s_setprio(1); MF16(S0a, S0b); __builtin_amdgcn_s_setprio(0);
        asm volatile("s_waitcnt vmcnt(0)" ::: "memory");   // (t+2) landed
        BAR();
        // ph4: prefetch (t+2).kk0 -> S0; stage t+3 -> buf1; compute (t+1).kk1; BAR
        RDA(S0a, 0, ck0); RDB(S0b, 0, ck0);                // stale on last iter: unused
        if (t3 < 32) { STAGEA(t3, 32768); STAGEB(t3, 16384); }
        __builtin_amdgcn_s_setprio(1); MF16(S1a, S1b); __builtin_amdgcn_s_setprio(0);
        BAR();
    }

    // ---- epilogue: rows = bm*256 + wm*128 + mf*16 + quad*4 + r
    //      cols = bn*128 + wn*16 + nf*64 + l16   (nf pairs are d, d+64)
    if (MODE == 0) {
#pragma unroll
        for (int mf = 0; mf < 8; mf++)
#pragma unroll
            for (int nf = 0; nf < 2; nf++) {
                int col = (bn << 7) + wn * 16 + nf * 64 + l16;
#pragma unroll
                for (int r = 0; r < 4; r++) {
                    int row = (bm << 8) + wm * 128 + mf * 16 + (quad << 2) + r;
                    Cp[(size_t)row * CCH + col] = acc[mf][nf][r];
                }
            }
    } else {
        int type = bn >> 4;              // 0=q, 1=k, 2=v (16 blocks per 2048-col chunk)
        int h = bn & 15;                 // one head per block
        int d1 = wn * 16 + l16;          // 0..63 (low half of head dim)
        if (type < 2) {
            f16* outp = (type == 0) ? qr : kr;
#pragma unroll
            for (int mf = 0; mf < 8; mf++)
#pragma unroll
                for (int r = 0; r < 4; r++) {
                    int row = (bm << 8) + wm * 128 + mf * 16 + (quad << 2) + r;
                    float2 tc = tab[row * 64 + d1];
                    float a1 = acc[mf][0][r], a2 = acc[mf][1][r];
                    float o1 = a1 * tc.x - a2 * tc.y;
                    float o2 = a2 * tc.x + a1 * tc.y;
                    if (type == 0) {
                        if (d1 == 63) o2 = 1.0f;          // q[...,-1]=1 (before scale)
                        o1 *= SCALE; o2 *= SCALE;
                    } else {
                        if (d1 == 63) o2 = cs[row];       // k[...,-1]=cum_scores
                    }
                    size_t ob = ((size_t)((row >> 10) * HH + h) * TT + (row & 1023)) * HDIM + d1;
                    outp[ob] = (f16)o1;
                    outp[ob + 64] = (f16)o2;
                }
        } else {
#pragma unroll
            for (int mf = 0; mf < 8; mf++)
#pragma unroll
                for (int r = 0; r < 4; r++) {
                    int row = (bm << 8) + wm * 128 + mf * 16 + (quad << 2) + r;
                    float ve = __expf(cs[row]);
                    size_t ob = ((size_t)((row >> 10) * HH + h) * TT + (row & 1023)) * HDIM + d1;
                    vsc[ob]      = (f16)(acc[mf][0][r] * ve);
                    vsc[ob + 64] = (f16)(acc[mf][1][r] * ve);
                }
        }
    }
}

// ---------------- causal flash attention, S^T formulation ----------------
__global__ __launch_bounds__(256) void k_attn(const f16* __restrict__ qr,
                                              const f16* __restrict__ kr,
                                              const f16* __restrict__ vt,
                                              const float* __restrict__ pb,
                                              f16* __restrict__ y) {
    __shared__ __align__(16) f16 Ks[64 * 136];   // [kv][hd], pad 128->136
    __shared__ __align__(16) f16 Vs[128 * 72];   // [hd][kv], pad 64->72
    __shared__ float pbs[64];
    int p = blockIdx.x & (NQT / 2 - 1);
    int bh = blockIdx.x >> 3;
    int b = bh >> 4, h = bh & 15;
    int tid = threadIdx.x;
    int w = tid >> 6, lane = tid & 63, quad = lane >> 4, l16 = lane & 15;
#pragma unroll
    for (int pass = 0; pass < 2; pass++) {
        int qt = pass ? (NQT - 1 - p) : p;
        int q0 = qt << 6;
        int qg = q0 + w * 16 + l16;                  // this lane's q column
        const f16* Qp = qr + ((size_t)bh * TT + qg) * HDIM;
        half8 qf[4];                                  // B-op: Q[q=l16][hd=kc*32+quad*8+e]
#pragma unroll
        for (int kc = 0; kc < 4; kc++) qf[kc] = *(const half8*)&Qp[kc * 32 + (quad << 3)];
        floatx4 O[8];                                 // O^T[hd][q] C-frags
#pragma unroll
        for (int i = 0; i < 8; i++) O[i] = (floatx4){0.f, 0.f, 0.f, 0.f};
        float mx = -1e30f, ls = 0.f;
        for (int kt = 0; kt <= qt; kt++) {
            __syncthreads();
            const f16* Kb = kr + ((size_t)bh * TT + (kt << 6)) * HDIM;
            const f16* Vb = vt + (size_t)bh * HDIM * TT + (kt << 6);
#pragma unroll
            for (int i = 0; i < 4; i++) {
                int seg = tid + (i << 8);
                int krow = seg >> 4, kcol = (seg & 15) << 3;
                *(uint4*)&Ks[krow * 136 + kcol] = *(const uint4*)&Kb[(size_t)krow * HDIM + kcol];
                int vrow = seg >> 3, vcol = (seg & 7) << 3;
                *(uint4*)&Vs[vrow * 72 + vcol] = *(const uint4*)&Vb[(size_t)vrow * TT + vcol];
            }
            if (tid < 64) pbs[tid] = pb[b * TT + (kt << 6) + tid];
            __syncthreads();
            // S^T = K * Q^T : C-layout S^T[kv=quad*4+i][q=l16]
            floatx4 Sv[4];
#pragma unroll
            for (int mc = 0; mc < 4; mc++) Sv[mc] = (floatx4){0.f, 0.f, 0.f, 0.f};
#pragma unroll
            for (int kc = 0; kc < 4; kc++)
#pragma unroll
                for (int mc = 0; mc < 4; mc++) {
                    half8 kf = *(const half8*)&Ks[(mc * 16 + l16) * 136 + kc * 32 + (quad << 3)];
                    Sv[mc] = __builtin_amdgcn_mfma_f32_16x16x32_f16(kf, qf[kc], Sv[mc], 0, 0, 0);
                }
            // mask + bias + online softmax (per q column = per lane)
            float pv[4][4];
            float mnew = mx;
#pragma unroll
            for (int mc = 0; mc < 4; mc++) {
                float4 pbv = *(const float4*)&pbs[mc * 16 + (quad << 2)];
#pragma unroll
                for (int i = 0; i < 4; i++) {
                    int kv = (kt << 6) + mc * 16 + (quad << 2) + i;
                    float s = (kv <= qg) ? Sv[mc][i] + ((const float*)&pbv)[i] : -1e30f;
                    pv[mc][i] = s;
                    mnew = fmaxf(mnew, s);
                }
            }
            mnew = fmaxf(mnew, __shfl_xor(mnew, 16));
            mnew = fmaxf(mnew, __shfl_xor(mnew, 32));
            float al = __expf(mx - mnew);
            mx = mnew;
            float psum = 0.f;
#pragma unroll
            for (int mc = 0; mc < 4; mc++)
#pragma unroll
                for (int i = 0; i < 4; i++) {
                    float e = __expf(pv[mc][i] - mnew);
                    pv[mc][i] = e;
                    psum += e;
                }
            psum += __shfl_xor(psum, 16);
            psum += __shfl_xor(psum, 32);
            ls = ls * al + psum;
#pragma unroll
            for (int hm = 0; hm < 8; hm++)
#pragma unroll
                for (int i = 0; i < 4; i++) O[hm][i] *= al;
            // P^T as B-operand of 16x16x16 (k=quad*4+i == C rows). A = V^T.
            half4 pf[4];
#pragma unroll
            for (int mc = 0; mc < 4; mc++) {
                pf[mc][0] = (f16)pv[mc][0]; pf[mc][1] = (f16)pv[mc][1];
                pf[mc][2] = (f16)pv[mc][2]; pf[mc][3] = (f16)pv[mc][3];
            }
#pragma unroll
            for (int mc = 0; mc < 4; mc++)
#pragma unroll
                for (int hm = 0; hm < 8; hm++) {
                    half4 vf = *(const half4*)&Vs[(hm * 16 + l16) * 72 + mc * 16 + (quad << 2)];
                    O[hm] = __builtin_amdgcn_mfma_f32_16x16x16f16(vf, pf[mc], O[hm], 0, 0, 0);
                }
        }
        float inv = 1.0f / ls;
#pragma unroll
        for (int hm = 0; hm < 8; hm++) {
            half4 ov;
#pragma unroll
            for (int i = 0; i < 4; i++) ov[i] = (f16)(O[hm][i] * inv);
            *(half4*)&y[((size_t)b * TT + qg) * CCH + h * HDIM + hm * 16 + (quad << 2)] = ov;
        }
        __syncthreads();   // protect LDS before next pass restages
    }
}

extern "C" void kernel_launch(void* const* d_in, const int* in_sizes, int n_in,
                              void* d_out, int out_size, void* d_ws, size_t ws_size,
                              hipStream_t stream) {
    const float* x   = (const float*)d_in[0];
    const float* cs  = (const float*)d_in[1];
    const int*   tok = (const int*)d_in[2];
    const int*   pm  = (const int*)d_in[3];
    const float* Wa  = (const float*)d_in[4];
    const float* Wp  = (const float*)d_in[5];
    float* out = (float*)d_out;
    char* ws = (char*)d_ws;

    f16* x16 = (f16*)(ws + 0);             // 16 MB ; reused as y after GEMM1
    f16* WaT = (f16*)(ws + 16777216);      // 24 MB
    f16* vt  = (f16*)(ws + 41943040);      // 16 MB   [bh][hd][t]
    f16* WpT = (f16*)(ws + 58720256);      //  8 MB
    float2* tab = (float2*)(ws + 67108864);// 2 MB rope table (gap before qr)
    f16* qr  = (f16*)(ws + 92274688);      // 16 MB
    f16* kr  = (f16*)(ws + 109051904);     // 16 MB
    f16* vsc = (f16*)(ws + 125829120);     // 16 MB
    int*   cnt  = (int*)(ws + 142606336);  // 4 KB
    float* tpos = (float*)(ws + 142610432);// 16 KB
    float* pb   = (float*)(ws + 142626816);// 16 KB
    f16* y   = x16;

    hipMemsetAsync(cnt, 0, NBLK * sizeof(int), stream);
    k_hist<<<MM / 256, 256, 0, stream>>>(tok, cnt);
    k_scan<<<BB, TT, 0, stream>>>(tok, cnt, pm, tpos, pb);
    k_rope<<<MM * 64 / 256, 256, 0, stream>>>(tpos, tab);
    k_prep<<<dim3(N1 / 32, CCH / 32, 3), dim3(32, 8), 0, stream>>>(Wa, Wp, x, WaT, WpT, x16);
    k_gemm8<1><<<768, 512, 0, stream>>>(x16, WaT, nullptr, tab, cs, qr, kr, vsc);
    k_trv<<<dim3(4, 32, BB * HH), dim3(32, 8), 0, stream>>>(vsc, vt);
    k_attn<<<BB * HH * (NQT / 2), 256, 0, stream>>>(qr, kr, vt, pb, y);
    k_gemm8<0><<<256, 512, 0, stream>>>(y, WpT, out, nullptr, nullptr, nullptr, nullptr, nullptr);
}